// Round 19
// baseline (417.673 us; speedup 1.0000x reference)
//
#include <hip/hip_runtime.h>
#include <hip/hip_fp16.h>
#include <cstdint>
#include <cstddef>

// ---------------------------------------------------------------------------
// GATv2 x2 + linear head on MI355X.
// pre{hist+eah-convert || wprep} -> 3-phase scan (rowstart+cursor) ->
// FAT{gemm1 || scatter-only(es int2, L2-merge-friendly) || dcount} ->
// dbase/dscatter (degree binning) -> fused L1 -> gemm2 -> fused L2 -> linear.
// Degree-ordered nodes; packed fp16 GEMV; MFMA GEMMs. No float atomics.
// ---------------------------------------------------------------------------

typedef _Float16 half8 __attribute__((ext_vector_type(8)));
typedef float f32x4 __attribute__((ext_vector_type(4)));

// ---- 3-phase exclusive scan of deg[0..n) -> rowstart[0..n] (+cursor) ----
__global__ void scan_part(const int* __restrict__ deg, int* __restrict__ bsum, int n) {
    int tid = threadIdx.x;
    int base = blockIdx.x * 1024 + tid * 4;
    int s = 0;
#pragma unroll
    for (int j = 0; j < 4; ++j) {
        int i = base + j;
        if (i < n) s += deg[i];
    }
#pragma unroll
    for (int off = 1; off < 64; off <<= 1) s += __shfl_xor(s, off, 64);
    __shared__ int ws[4];
    if ((tid & 63) == 0) ws[tid >> 6] = s;
    __syncthreads();
    if (tid == 0) bsum[blockIdx.x] = ws[0] + ws[1] + ws[2] + ws[3];
}

__global__ void scan_mid(int* __restrict__ bsum, int* __restrict__ rowstart, int nb, int n) {
    int tid = threadIdx.x;
    int v = (tid < nb) ? bsum[tid] : 0;
    int incl = v;
#pragma unroll
    for (int off = 1; off < 64; off <<= 1) {
        int t = __shfl_up(incl, off, 64);
        if ((tid & 63) >= off) incl += t;
    }
    __shared__ int w0;
    if (tid == 63) w0 = incl;
    __syncthreads();
    if (tid >= 64) incl += w0;
    if (tid < nb) bsum[tid] = incl - v;
    if (tid == nb - 1) rowstart[n] = incl;
}

__global__ void scan_fin(const int* __restrict__ deg, const int* __restrict__ bsum,
                         int* __restrict__ rowstart, int* __restrict__ cursor, int n) {
    int tid = threadIdx.x;
    int lane = tid & 63, wid = tid >> 6;
    int base = blockIdx.x * 1024 + tid * 4;
    int v[4];
    int s = 0;
#pragma unroll
    for (int j = 0; j < 4; ++j) {
        int i = base + j;
        v[j] = (i < n) ? deg[i] : 0;
        s += v[j];
    }
    int incl = s;
#pragma unroll
    for (int off = 1; off < 64; off <<= 1) {
        int t = __shfl_up(incl, off, 64);
        if (lane >= off) incl += t;
    }
    __shared__ int ws[4];
    if (lane == 63) ws[wid] = incl;
    __syncthreads();
    int wofs = 0;
    for (int w2 = 0; w2 < wid; ++w2) wofs += ws[w2];
    int acc = bsum[blockIdx.x] + wofs + (incl - s);
#pragma unroll
    for (int j = 0; j < 4; ++j) {
        int i = base + j;
        if (i < n) {
            rowstart[i] = acc;
            cursor[i] = acc;
        }
        acc += v[j];
    }
}

// Repack [Wl|Wr] into MFMA B-fragment order.
template <int K, int Mh>
__device__ void wprep_body(int i, const float* __restrict__ Wl, const float* __restrict__ Wr,
                           __half* __restrict__ Wfrag) {
    constexpr int KS = K / 32;
    if (i >= K * 2 * Mh) return;
    int j = i & 7;
    int lane = (i >> 3) & 63;
    int rest = i >> 9;
    int ks = rest % KS;
    int nt = rest / KS;
    int k = ks * 32 + ((lane >> 4) & 3) * 8 + j;
    int col = nt * 16 + (lane & 15);
    float v = (col < Mh) ? Wl[k * Mh + col] : Wr[k * Mh + (col - Mh)];
    Wfrag[i] = __float2half(v);
}

// PRE kernel: {hist (fire-and-forget atomic) + eah fp16 convert} || wprep.
__global__ void pre_kernel(int nbH, const int* __restrict__ dst, int* __restrict__ deg,
                           const float* __restrict__ eattr, __half* __restrict__ eah, int E,
                           const float* W1l, const float* W1r, __half* Wf1,
                           const float* W2l, const float* W2r, __half* Wf2) {
    int bid = blockIdx.x;
    int tid = threadIdx.x;
    if (bid < nbH) {
        int e = bid * 256 + tid;
        if (e < E) {
            atomicAdd(&deg[dst[e]], 1);  // fire-and-forget
            const float4* s4 = (const float4*)&eattr[(size_t)e * 16];
            float4 a = s4[0], b = s4[1], c = s4[2], f = s4[3];
            __half2 h[8];
            h[0] = __float22half2_rn(make_float2(a.x, a.y));
            h[1] = __float22half2_rn(make_float2(a.z, a.w));
            h[2] = __float22half2_rn(make_float2(b.x, b.y));
            h[3] = __float22half2_rn(make_float2(b.z, b.w));
            h[4] = __float22half2_rn(make_float2(c.x, c.y));
            h[5] = __float22half2_rn(make_float2(c.z, c.w));
            h[6] = __float22half2_rn(make_float2(f.x, f.y));
            h[7] = __float22half2_rn(make_float2(f.z, f.w));
            int4* o = (int4*)&eah[(size_t)e * 16];
            o[0] = *(int4*)&h[0];
            o[1] = *(int4*)&h[4];
        }
    } else {
        int wb = bid - nbH;
        if (wb < 64) wprep_body<128, 64>(wb * 256 + tid, W1l, W1r, Wf1);
        else         wprep_body<64, 32>((wb - 64) * 256 + tid, W2l, W2r, Wf2);
    }
}

// ---- MFMA dual GEMM body (fp32 input) ----
template <int K, int Mh, int BM>
__device__ void gemm_body(int bid, __half* xs, const float* __restrict__ x,
                          const __half* __restrict__ Wfrag, const float* __restrict__ bl,
                          const float* __restrict__ br, __half* __restrict__ yl,
                          __half* __restrict__ yr, int n) {
    constexpr int KS = K / 32;
    constexpr int NT = (2 * Mh) / 16;
    constexpr int RW = BM / 64;
    constexpr int LDP = K + 8;
    int tid = threadIdx.x;
    int lane = tid & 63;
    int wave = tid >> 6;
    int node0 = bid * BM;
    constexpr int ITER = (BM * K) / (256 * 4);
#pragma unroll
    for (int it = 0; it < ITER; ++it) {
        int base = (it * 256 + tid) * 4;
        int row = base / K, kk = base % K;
        float4 v = make_float4(0.f, 0.f, 0.f, 0.f);
        if (node0 + row < n) v = *(const float4*)&x[(size_t)(node0 + row) * K + kk];
        __half2* d = (__half2*)&xs[row * LDP + kk];
        d[0] = __float22half2_rn(make_float2(v.x, v.y));
        d[1] = __float22half2_rn(make_float2(v.z, v.w));
    }
    __syncthreads();
    f32x4 acc[RW][NT];
#pragma unroll
    for (int r = 0; r < RW; ++r)
#pragma unroll
        for (int t = 0; t < NT; ++t) {
            f32x4 z = {0.f, 0.f, 0.f, 0.f};
            acc[r][t] = z;
        }
    int r0 = lane & 15, kof = (lane >> 4) * 8;
#pragma unroll
    for (int ks = 0; ks < KS; ++ks) {
        half8 a[RW];
#pragma unroll
        for (int r = 0; r < RW; ++r) {
            int row = (wave * RW + r) * 16 + r0;
            a[r] = *reinterpret_cast<const half8*>(&xs[row * LDP + ks * 32 + kof]);
        }
#pragma unroll
        for (int t = 0; t < NT; ++t) {
            half8 b = *reinterpret_cast<const half8*>(&Wfrag[(((size_t)t * KS + ks) * 64 + lane) * 8]);
#pragma unroll
            for (int r = 0; r < RW; ++r)
                acc[r][t] = __builtin_amdgcn_mfma_f32_16x16x32_f16(a[r], b, acc[r][t], 0, 0, 0);
        }
    }
#pragma unroll
    for (int r = 0; r < RW; ++r) {
#pragma unroll
        for (int t = 0; t < NT; ++t) {
            int col = t * 16 + (lane & 15);
            float bv = (col < Mh) ? bl[col] : br[col - Mh];
#pragma unroll
            for (int q = 0; q < 4; ++q) {
                int node = node0 + (wave * RW + r) * 16 + (lane >> 4) * 4 + q;
                if (node < n) {
                    float v = acc[r][t][q] + bv;
                    if (col < Mh) yl[(size_t)node * Mh + col] = __float2half(v);
                    else          yr[(size_t)node * Mh + (col - Mh)] = __float2half(v);
                }
            }
        }
    }
}

// fp16-input gemm body for layer 2
template <int K, int Mh, int BM>
__device__ void gemm_body_h(int bid, __half* xs, const __half* __restrict__ x,
                            const __half* __restrict__ Wfrag, const float* __restrict__ bl,
                            const float* __restrict__ br, __half* __restrict__ yl,
                            __half* __restrict__ yr, int n) {
    constexpr int KS = K / 32;
    constexpr int NT = (2 * Mh) / 16;
    constexpr int RW = BM / 64;
    constexpr int LDP = K + 8;
    int tid = threadIdx.x;
    int lane = tid & 63;
    int wave = tid >> 6;
    int node0 = bid * BM;
    constexpr int ITER = (BM * K) / (256 * 8);
#pragma unroll
    for (int it = 0; it < ITER; ++it) {
        int base = (it * 256 + tid) * 8;
        int row = base / K, kk = base % K;
        int4 v = make_int4(0, 0, 0, 0);
        if (node0 + row < n) v = *(const int4*)&x[(size_t)(node0 + row) * K + kk];
        *(int4*)&xs[row * LDP + kk] = v;
    }
    __syncthreads();
    f32x4 acc[RW][NT];
#pragma unroll
    for (int r = 0; r < RW; ++r)
#pragma unroll
        for (int t = 0; t < NT; ++t) {
            f32x4 z = {0.f, 0.f, 0.f, 0.f};
            acc[r][t] = z;
        }
    int r0 = lane & 15, kof = (lane >> 4) * 8;
#pragma unroll
    for (int ks = 0; ks < KS; ++ks) {
        half8 a[RW];
#pragma unroll
        for (int r = 0; r < RW; ++r) {
            int row = (wave * RW + r) * 16 + r0;
            a[r] = *reinterpret_cast<const half8*>(&xs[row * LDP + ks * 32 + kof]);
        }
#pragma unroll
        for (int t = 0; t < NT; ++t) {
            half8 b = *reinterpret_cast<const half8*>(&Wfrag[(((size_t)t * KS + ks) * 64 + lane) * 8]);
#pragma unroll
            for (int r = 0; r < RW; ++r)
                acc[r][t] = __builtin_amdgcn_mfma_f32_16x16x32_f16(a[r], b, acc[r][t], 0, 0, 0);
        }
    }
#pragma unroll
    for (int r = 0; r < RW; ++r) {
#pragma unroll
        for (int t = 0; t < NT; ++t) {
            int col = t * 16 + (lane & 15);
            float bv = (col < Mh) ? bl[col] : br[col - Mh];
#pragma unroll
            for (int q = 0; q < 4; ++q) {
                int node = node0 + (wave * RW + r) * 16 + (lane >> 4) * 4 + q;
                if (node < n) {
                    float v = acc[r][t][q] + bv;
                    if (col < Mh) yl[(size_t)node * Mh + col] = __float2half(v);
                    else          yr[(size_t)node * Mh + (col - Mh)] = __float2half(v);
                }
            }
        }
    }
}

// Scatter-only: dst/src reads + cursor atomic + es random 8B write.
// No eattr streaming -> es lines survive in L2 and write-combine.
__device__ void scatter_body(int e, const int* __restrict__ src, const int* __restrict__ dst,
                             int* __restrict__ cursor, int2* __restrict__ es, int E) {
    if (e < E) {
        int d = dst[e];
        int pos = atomicAdd(&cursor[d], 1);
        es[pos] = make_int2(e, src[e]);
    }
}

__device__ void dcount_body(int bid, int* h, const int* __restrict__ deg,
                            int* __restrict__ counts, int n) {
    int tid = threadIdx.x;
    h[tid] = 0;
    __syncthreads();
    int base = bid * 4096;
#pragma unroll
    for (int j = 0; j < 16; ++j) {
        int i = base + j * 256 + tid;
        if (i < n) {
            int b = deg[i];
            b = (b > 255) ? 255 : b;
            atomicAdd(&h[b], 1);
        }
    }
    __syncthreads();
    counts[bid * 256 + tid] = h[tid];
}

// FAT kernel: gemm1 || scatter-only || dcount
__global__ __launch_bounds__(256) void fat_kernel(
    int nbG, int nbS,
    const float* __restrict__ x, const __half* __restrict__ Wf1,
    const float* __restrict__ b1l, const float* __restrict__ b1r,
    __half* __restrict__ A, __half* __restrict__ B, int n,
    const int* __restrict__ src, const int* __restrict__ dst,
    int* __restrict__ cursor, int2* __restrict__ es, int E,
    const int* __restrict__ deg, int* __restrict__ counts) {
    __shared__ __half xs[64 * 136];
    __shared__ int hcnt[256];
    int bid = blockIdx.x;
    if (bid < nbG) {
        gemm_body<128, 64, 64>(bid, xs, x, Wf1, b1l, b1r, A, B, n);
    } else if (bid < nbG + nbS) {
        scatter_body((bid - nbG) * 256 + threadIdx.x, src, dst, cursor, es, E);
    } else {
        dcount_body(bid - nbG - nbS, hcnt, deg, counts, n);
    }
}

// one 256-thread block: bin totals -> bin starts -> per-block bases
__global__ void dbase_kernel(const int* __restrict__ counts, int* __restrict__ base, int nblk) {
    int b = threadIdx.x;
    int tot = 0;
    for (int k = 0; k < nblk; ++k) tot += counts[k * 256 + b];
    __shared__ int ws[4];
    int lane = b & 63, wid = b >> 6;
    int incl = tot;
#pragma unroll
    for (int off = 1; off < 64; off <<= 1) {
        int t = __shfl_up(incl, off, 64);
        if (lane >= off) incl += t;
    }
    if (lane == 63) ws[wid] = incl;
    __syncthreads();
    int wofs = 0;
    for (int w = 0; w < wid; ++w) wofs += ws[w];
    int acc = wofs + incl - tot;
    for (int k = 0; k < nblk; ++k) {
        base[k * 256 + b] = acc;
        acc += counts[k * 256 + b];
    }
}

__global__ __launch_bounds__(256) void dscatter_block(const int* __restrict__ deg,
                                                      const int* __restrict__ base,
                                                      int* __restrict__ nodeperm, int n) {
    __shared__ int h[256];
    int tid = threadIdx.x;
    h[tid] = 0;
    __syncthreads();
    int bbase = blockIdx.x * 4096;
#pragma unroll
    for (int j = 0; j < 16; ++j) {
        int i = bbase + j * 256 + tid;
        if (i < n) {
            int b = deg[i];
            b = (b > 255) ? 255 : b;
            int r = atomicAdd(&h[b], 1);
            nodeperm[base[blockIdx.x * 256 + b] + r] = i;
        }
    }
}

// standalone gemm for layer 2 (fp16 input)
template <int K, int Mh, int BM>
__global__ __launch_bounds__(256) void gemm_mfma_h(
    const __half* __restrict__ x, const __half* __restrict__ Wfrag,
    const float* __restrict__ bl, const float* __restrict__ br,
    __half* __restrict__ yl, __half* __restrict__ yr, int n) {
    __shared__ __half xs[BM * (K + 8)];
    gemm_body_h<K, Mh, BM>(blockIdx.x, xs, x, Wfrag, bl, br, yl, yr, n);
}

// y[n,M] = x[n,K] @ W[K,M] + b ; fp16 input, fp32 math (final head)
template <int K, int M, int NPB>
__global__ void linear_kernel(const __half* __restrict__ x, const float* __restrict__ W,
                              const float* __restrict__ b, float* __restrict__ y, int n) {
    __shared__ float sx[NPB * K];
    int tid = threadIdx.x;
    int node0 = blockIdx.x * NPB;
    for (int i = tid; i < NPB * K; i += NPB * M) {
        int nn = node0 + i / K;
        sx[i] = (nn < n) ? __half2float(x[(size_t)nn * K + (i % K)]) : 0.f;
    }
    __syncthreads();
    int ln = tid / M, m = tid % M;
    int node = node0 + ln;
    if (node >= n) return;
    float acc = b[m];
#pragma unroll
    for (int k = 0; k < K; ++k) acc = fmaf(sx[ln * K + k], W[k * M + m], acc);
    y[(size_t)node * M + m] = acc;
}

// FUSED edge-logit + softmax + aggregate (round-12 form, fp16 output).
template <int H, int C>
__global__ __launch_bounds__(256) void fused_edge_agg(
    const int* __restrict__ rowstart, const int2* __restrict__ es,
    const __half* __restrict__ eah, const int* __restrict__ nodeperm,
    const float* __restrict__ We,    // [16, HC]
    const float* __restrict__ att,   // [HC]
    const __half* __restrict__ xl, const __half* __restrict__ xr,
    const float* __restrict__ bias, __half* __restrict__ out, int n) {
    constexpr int HC = H * C;
    constexpr int LPN = HC / 2;
    constexpr int NPW = 64 / LPN;
    int gt = blockIdx.x * blockDim.x + threadIdx.x;
    int wave = gt >> 6;
    int lane = threadIdx.x & 63;
    int sub = lane / LPN;
    int j = lane % LPN;
    int ch0 = 2 * j;
    int slot = wave * NPW + sub;
    if (slot >= n) return;
    int node = nodeperm[slot];
    __half2 wh[16];
#pragma unroll
    for (int k = 0; k < 16; ++k) wh[k] = __float22half2_rn(*(const float2*)&We[k * HC + ch0]);
    float2 a2 = *(const float2*)&att[ch0];
    float2 xr2 = __half22float2(*(const __half2*)&xr[(size_t)node * HC + ch0]);
    int beg = rowstart[node], end = rowstart[node + 1];
    float denom = 0.f, acc0 = 0.f, acc1 = 0.f;

    auto gemv = [&](const float4& r0, const float4& r1, const __half2& xlh,
                    float& m0, float& m1, float2& xlf) {
        const __half2* h0 = (const __half2*)&r0;
        const __half2* h1 = (const __half2*)&r1;
        __half2 p0 = __hmul2(__low2half2(h0[0]), wh[0]);
        __half2 p1 = __hmul2(__high2half2(h0[0]), wh[1]);
        p0 = __hfma2(__low2half2(h0[1]), wh[2], p0);
        p1 = __hfma2(__high2half2(h0[1]), wh[3], p1);
        p0 = __hfma2(__low2half2(h0[2]), wh[4], p0);
        p1 = __hfma2(__high2half2(h0[2]), wh[5], p1);
        p0 = __hfma2(__low2half2(h0[3]), wh[6], p0);
        p1 = __hfma2(__high2half2(h0[3]), wh[7], p1);
        p0 = __hfma2(__low2half2(h1[0]), wh[8], p0);
        p1 = __hfma2(__high2half2(h1[0]), wh[9], p1);
        p0 = __hfma2(__low2half2(h1[1]), wh[10], p0);
        p1 = __hfma2(__high2half2(h1[1]), wh[11], p1);
        p0 = __hfma2(__low2half2(h1[2]), wh[12], p0);
        p1 = __hfma2(__high2half2(h1[2]), wh[13], p1);
        p0 = __hfma2(__low2half2(h1[3]), wh[14], p0);
        p1 = __hfma2(__high2half2(h1[3]), wh[15], p1);
        float2 mf = __half22float2(__hadd2(p0, p1));
        xlf = __half22float2(xlh);
        m0 = xlf.x + xr2.x + mf.x;
        m1 = xlf.y + xr2.y + mf.y;
    };
    auto logit = [&](float m0, float m1) -> float {
        m0 = (m0 > 0.f) ? m0 : 0.2f * m0;
        m1 = (m1 > 0.f) ? m1 : 0.2f * m1;
        float v = m0 * a2.x + m1 * a2.y;
#pragma unroll
        for (int msk = 1; msk < 16; msk <<= 1) v += __shfl_xor(v, msk, 64);
        return v;
    };

    int pp = beg;
    for (; pp + 2 <= end; pp += 2) {
        int2 ea = es[pp];
        int2 eb = es[pp + 1];
        const float4* qa = (const float4*)&eah[(size_t)ea.x * 16];
        const float4* qb = (const float4*)&eah[(size_t)eb.x * 16];
        float4 r0a = qa[0], r1a = qa[1];
        float4 r0b = qb[0], r1b = qb[1];
        __half2 xh0 = *(const __half2*)&xl[(size_t)ea.y * HC + ch0];
        __half2 xh1 = *(const __half2*)&xl[(size_t)eb.y * HC + ch0];
        float m0a, m1a, m0b, m1b;
        float2 xla, xlb;
        gemv(r0a, r1a, xh0, m0a, m1a, xla);
        gemv(r0b, r1b, xh1, m0b, m1b, xlb);
        float wa = __expf(logit(m0a, m1a));
        float wb = __expf(logit(m0b, m1b));
        denom += wa + wb;
        acc0 = fmaf(xla.x, wa, acc0);
        acc1 = fmaf(xla.y, wa, acc1);
        acc0 = fmaf(xlb.x, wb, acc0);
        acc1 = fmaf(xlb.y, wb, acc1);
    }
    if (pp < end) {
        int2 ea = es[pp];
        const float4* qa = (const float4*)&eah[(size_t)ea.x * 16];
        float4 r0a = qa[0], r1a = qa[1];
        __half2 xh0 = *(const __half2*)&xl[(size_t)ea.y * HC + ch0];
        float m0a, m1a;
        float2 xla;
        gemv(r0a, r1a, xh0, m0a, m1a, xla);
        float wa = __expf(logit(m0a, m1a));
        denom += wa;
        acc0 = fmaf(xla.x, wa, acc0);
        acc1 = fmaf(xla.y, wa, acc1);
    }
    float2 b2 = *(const float2*)&bias[ch0];
    float inv = 1.f / (denom + 1e-16f);
    float o0 = acc0 * inv + b2.x;
    float o1 = acc1 * inv + b2.y;
    o0 = (o0 > 0.f) ? o0 : __expf(o0) - 1.f;
    o1 = (o1 > 0.f) ? o1 : __expf(o1) - 1.f;
    *(__half2*)&out[(size_t)node * HC + ch0] = __float22half2_rn(make_float2(o0, o1));
}

extern "C" void kernel_launch(void* const* d_in, const int* in_sizes, int n_in,
                              void* d_out, int out_size, void* d_ws, size_t ws_size,
                              hipStream_t stream) {
    const float* x     = (const float*)d_in[0];
    const int*   eidx  = (const int*)d_in[1];
    const float* eattr = (const float*)d_in[2];
    const float* W1l   = (const float*)d_in[3];
    const float* b1l   = (const float*)d_in[4];
    const float* W1r   = (const float*)d_in[5];
    const float* b1r   = (const float*)d_in[6];
    const float* W1e   = (const float*)d_in[7];
    const float* att1  = (const float*)d_in[8];
    const float* bias1 = (const float*)d_in[9];
    const float* W2l   = (const float*)d_in[10];
    const float* b2l   = (const float*)d_in[11];
    const float* W2r   = (const float*)d_in[12];
    const float* b2r   = (const float*)d_in[13];
    const float* W2e   = (const float*)d_in[14];
    const float* att2  = (const float*)d_in[15];
    const float* bias2 = (const float*)d_in[16];
    const float* Wlin  = (const float*)d_in[17];
    const float* blin  = (const float*)d_in[18];

    const int N = in_sizes[0] / 128;
    const int E = in_sizes[1] / 2;
    const int* src = eidx;
    const int* dst = eidx + E;
    const int NB_DC = (N + 4095) / 4096;

    char* p = (char*)d_ws;
    auto take = [&](size_t bytes) {
        char* r = p;
        p += (bytes + 255) & ~(size_t)255;
        return r;
    };
    int*    deg      = (int*)take((size_t)N * sizeof(int));
    char*   zero_end = p;
    int*    cursor   = (int*)take((size_t)N * sizeof(int));
    int*    rowstart = (int*)take((size_t)(N + 1) * sizeof(int));
    int*    bsum     = (int*)take(256 * sizeof(int));
    int*    counts   = (int*)take((size_t)(NB_DC + 1) * 256 * sizeof(int));
    int*    dbase    = (int*)take((size_t)(NB_DC + 1) * 256 * sizeof(int));
    int*    nodeperm = (int*)take((size_t)N * sizeof(int));
    int2*   es       = (int2*)take((size_t)E * sizeof(int2));
    __half* eah      = (__half*)take((size_t)E * 16 * sizeof(__half));
    __half* A        = (__half*)take((size_t)N * 64 * sizeof(__half));
    __half* B        = (__half*)take((size_t)N * 64 * sizeof(__half));
    __half* Chalf    = (__half*)take((size_t)N * 64 * sizeof(__half));
    __half* Wf1      = (__half*)take((size_t)128 * 128 * sizeof(__half));
    __half* Wf2      = (__half*)take((size_t)64 * 64 * sizeof(__half));

    // ---- zero deg + pre {hist+eah || wprep} + scan (rowstart+cursor) ----
    (void)hipMemsetAsync(deg, 0, (size_t)(zero_end - (char*)deg), stream);
    {
        int nbH = (E + 255) / 256;
        pre_kernel<<<nbH + 80, 256, 0, stream>>>(nbH, dst, deg, eattr, eah, E,
                                                 W1l, W1r, Wf1, W2l, W2r, Wf2);
    }
    {
        int nb = (N + 1023) / 1024;
        scan_part<<<nb, 256, 0, stream>>>(deg, bsum, N);
        scan_mid<<<1, 128, 0, stream>>>(bsum, rowstart, nb, N);
        scan_fin<<<nb, 256, 0, stream>>>(deg, bsum, rowstart, cursor, N);
    }

    // ---- FAT: gemm1 || scatter-only || dcount ----
    {
        int nbG = (N + 63) / 64;
        int nbS = (E + 255) / 256;
        fat_kernel<<<nbG + nbS + NB_DC, 256, 0, stream>>>(
            nbG, nbS, x, Wf1, b1l, b1r, A, B, N, src, dst, cursor, es, E, deg, counts);
    }
    dbase_kernel<<<1, 256, 0, stream>>>(counts, dbase, NB_DC);
    dscatter_block<<<NB_DC, 256, 0, stream>>>(deg, dbase, nodeperm, N);

    // ---- Layer 1: H=2, C=32 (2 nodes/wave) ----
    {
        long waves = (N + 1) / 2;
        fused_edge_agg<2, 32><<<(int)((waves * 64 + 255) / 256), 256, 0, stream>>>(
            rowstart, es, eah, nodeperm, W1e, att1, A, B, bias1, Chalf, N);
    }

    // ---- Layer 2: H=1, C=32 (4 nodes/wave) ----
    gemm_mfma_h<64, 32, 128><<<(N + 127) / 128, 256, 0, stream>>>(Chalf, Wf2, b2l, b2r, A, B, N);
    {
        long waves = (N + 3) / 4;
        fused_edge_agg<1, 32><<<(int)((waves * 64 + 255) / 256), 256, 0, stream>>>(
            rowstart, es, eah, nodeperm, W2e, att2, A, B, bias2, Chalf, N);
    }

    // ---- Final linear ----
    linear_kernel<32, 32, 8><<<(N + 7) / 8, 256, 0, stream>>>(Chalf, Wlin, blin, (float*)d_out, N);
}

// Round 20
// 403.143 us; speedup vs baseline: 1.0360x; 1.0360x over previous
//
#include <hip/hip_runtime.h>
#include <hip/hip_fp16.h>
#include <cstdint>
#include <cstddef>

// ---------------------------------------------------------------------------
// GATv2 x2 + linear head on MI355X.  (round-18 config + pipelined fused loop)
// hist -> 3-phase scan (rowstart+cursor) -> wprep -> FAT{gemm1 || scatter(es
// int2 + eah fp16) || dcount} -> dbase/dscatter (degree binning) -> fused L1
// -> gemm2 -> fused L2 -> linear. Degree-ordered nodes; packed fp16 GEMV;
// MFMA GEMMs; 3-stage software pipeline in fused kernels. No float atomics.
// ---------------------------------------------------------------------------

typedef _Float16 half8 __attribute__((ext_vector_type(8)));
typedef float f32x4 __attribute__((ext_vector_type(4)));

__global__ void hist_kernel(const int* __restrict__ dst, int* __restrict__ deg, int E) {
    int e = blockIdx.x * blockDim.x + threadIdx.x;
    if (e < E) atomicAdd(&deg[dst[e]], 1);
}

// ---- 3-phase exclusive scan of deg[0..n) -> rowstart[0..n] (+cursor) ----
__global__ void scan_part(const int* __restrict__ deg, int* __restrict__ bsum, int n) {
    int tid = threadIdx.x;
    int base = blockIdx.x * 1024 + tid * 4;
    int s = 0;
#pragma unroll
    for (int j = 0; j < 4; ++j) {
        int i = base + j;
        if (i < n) s += deg[i];
    }
#pragma unroll
    for (int off = 1; off < 64; off <<= 1) s += __shfl_xor(s, off, 64);
    __shared__ int ws[4];
    if ((tid & 63) == 0) ws[tid >> 6] = s;
    __syncthreads();
    if (tid == 0) bsum[blockIdx.x] = ws[0] + ws[1] + ws[2] + ws[3];
}

__global__ void scan_mid(int* __restrict__ bsum, int* __restrict__ rowstart, int nb, int n) {
    int tid = threadIdx.x;
    int v = (tid < nb) ? bsum[tid] : 0;
    int incl = v;
#pragma unroll
    for (int off = 1; off < 64; off <<= 1) {
        int t = __shfl_up(incl, off, 64);
        if ((tid & 63) >= off) incl += t;
    }
    __shared__ int w0;
    if (tid == 63) w0 = incl;
    __syncthreads();
    if (tid >= 64) incl += w0;
    if (tid < nb) bsum[tid] = incl - v;
    if (tid == nb - 1) rowstart[n] = incl;
}

__global__ void scan_fin(const int* __restrict__ deg, const int* __restrict__ bsum,
                         int* __restrict__ rowstart, int* __restrict__ cursor, int n) {
    int tid = threadIdx.x;
    int lane = tid & 63, wid = tid >> 6;
    int base = blockIdx.x * 1024 + tid * 4;
    int v[4];
    int s = 0;
#pragma unroll
    for (int j = 0; j < 4; ++j) {
        int i = base + j;
        v[j] = (i < n) ? deg[i] : 0;
        s += v[j];
    }
    int incl = s;
#pragma unroll
    for (int off = 1; off < 64; off <<= 1) {
        int t = __shfl_up(incl, off, 64);
        if (lane >= off) incl += t;
    }
    __shared__ int ws[4];
    if (lane == 63) ws[wid] = incl;
    __syncthreads();
    int wofs = 0;
    for (int w2 = 0; w2 < wid; ++w2) wofs += ws[w2];
    int acc = bsum[blockIdx.x] + wofs + (incl - s);
#pragma unroll
    for (int j = 0; j < 4; ++j) {
        int i = base + j;
        if (i < n) {
            rowstart[i] = acc;
            cursor[i] = acc;
        }
        acc += v[j];
    }
}

// Repack [Wl|Wr] into MFMA B-fragment order; two weight sets in one launch.
template <int K, int Mh>
__device__ void wprep_body(int i, const float* __restrict__ Wl, const float* __restrict__ Wr,
                           __half* __restrict__ Wfrag) {
    constexpr int KS = K / 32;
    if (i >= K * 2 * Mh) return;
    int j = i & 7;
    int lane = (i >> 3) & 63;
    int rest = i >> 9;
    int ks = rest % KS;
    int nt = rest / KS;
    int k = ks * 32 + ((lane >> 4) & 3) * 8 + j;
    int col = nt * 16 + (lane & 15);
    float v = (col < Mh) ? Wl[k * Mh + col] : Wr[k * Mh + (col - Mh)];
    Wfrag[i] = __float2half(v);
}

__global__ void wprep_both(const float* W1l, const float* W1r, __half* Wf1,
                           const float* W2l, const float* W2r, __half* Wf2) {
    int bid = blockIdx.x;
    int tid = threadIdx.x;
    if (bid < 64) wprep_body<128, 64>(bid * 256 + tid, W1l, W1r, Wf1);
    else          wprep_body<64, 32>((bid - 64) * 256 + tid, W2l, W2r, Wf2);
}

// ---- MFMA dual GEMM body (fp32 input) ----
template <int K, int Mh, int BM>
__device__ void gemm_body(int bid, __half* xs, const float* __restrict__ x,
                          const __half* __restrict__ Wfrag, const float* __restrict__ bl,
                          const float* __restrict__ br, __half* __restrict__ yl,
                          __half* __restrict__ yr, int n) {
    constexpr int KS = K / 32;
    constexpr int NT = (2 * Mh) / 16;
    constexpr int RW = BM / 64;
    constexpr int LDP = K + 8;
    int tid = threadIdx.x;
    int lane = tid & 63;
    int wave = tid >> 6;
    int node0 = bid * BM;
    constexpr int ITER = (BM * K) / (256 * 4);
#pragma unroll
    for (int it = 0; it < ITER; ++it) {
        int base = (it * 256 + tid) * 4;
        int row = base / K, kk = base % K;
        float4 v = make_float4(0.f, 0.f, 0.f, 0.f);
        if (node0 + row < n) v = *(const float4*)&x[(size_t)(node0 + row) * K + kk];
        __half2* d = (__half2*)&xs[row * LDP + kk];
        d[0] = __float22half2_rn(make_float2(v.x, v.y));
        d[1] = __float22half2_rn(make_float2(v.z, v.w));
    }
    __syncthreads();
    f32x4 acc[RW][NT];
#pragma unroll
    for (int r = 0; r < RW; ++r)
#pragma unroll
        for (int t = 0; t < NT; ++t) {
            f32x4 z = {0.f, 0.f, 0.f, 0.f};
            acc[r][t] = z;
        }
    int r0 = lane & 15, kof = (lane >> 4) * 8;
#pragma unroll
    for (int ks = 0; ks < KS; ++ks) {
        half8 a[RW];
#pragma unroll
        for (int r = 0; r < RW; ++r) {
            int row = (wave * RW + r) * 16 + r0;
            a[r] = *reinterpret_cast<const half8*>(&xs[row * LDP + ks * 32 + kof]);
        }
#pragma unroll
        for (int t = 0; t < NT; ++t) {
            half8 b = *reinterpret_cast<const half8*>(&Wfrag[(((size_t)t * KS + ks) * 64 + lane) * 8]);
#pragma unroll
            for (int r = 0; r < RW; ++r)
                acc[r][t] = __builtin_amdgcn_mfma_f32_16x16x32_f16(a[r], b, acc[r][t], 0, 0, 0);
        }
    }
#pragma unroll
    for (int r = 0; r < RW; ++r) {
#pragma unroll
        for (int t = 0; t < NT; ++t) {
            int col = t * 16 + (lane & 15);
            float bv = (col < Mh) ? bl[col] : br[col - Mh];
#pragma unroll
            for (int q = 0; q < 4; ++q) {
                int node = node0 + (wave * RW + r) * 16 + (lane >> 4) * 4 + q;
                if (node < n) {
                    float v = acc[r][t][q] + bv;
                    if (col < Mh) yl[(size_t)node * Mh + col] = __float2half(v);
                    else          yr[(size_t)node * Mh + (col - Mh)] = __float2half(v);
                }
            }
        }
    }
}

// fp16-input gemm body for layer 2
template <int K, int Mh, int BM>
__device__ void gemm_body_h(int bid, __half* xs, const __half* __restrict__ x,
                            const __half* __restrict__ Wfrag, const float* __restrict__ bl,
                            const float* __restrict__ br, __half* __restrict__ yl,
                            __half* __restrict__ yr, int n) {
    constexpr int KS = K / 32;
    constexpr int NT = (2 * Mh) / 16;
    constexpr int RW = BM / 64;
    constexpr int LDP = K + 8;
    int tid = threadIdx.x;
    int lane = tid & 63;
    int wave = tid >> 6;
    int node0 = bid * BM;
    constexpr int ITER = (BM * K) / (256 * 8);
#pragma unroll
    for (int it = 0; it < ITER; ++it) {
        int base = (it * 256 + tid) * 8;
        int row = base / K, kk = base % K;
        int4 v = make_int4(0, 0, 0, 0);
        if (node0 + row < n) v = *(const int4*)&x[(size_t)(node0 + row) * K + kk];
        *(int4*)&xs[row * LDP + kk] = v;
    }
    __syncthreads();
    f32x4 acc[RW][NT];
#pragma unroll
    for (int r = 0; r < RW; ++r)
#pragma unroll
        for (int t = 0; t < NT; ++t) {
            f32x4 z = {0.f, 0.f, 0.f, 0.f};
            acc[r][t] = z;
        }
    int r0 = lane & 15, kof = (lane >> 4) * 8;
#pragma unroll
    for (int ks = 0; ks < KS; ++ks) {
        half8 a[RW];
#pragma unroll
        for (int r = 0; r < RW; ++r) {
            int row = (wave * RW + r) * 16 + r0;
            a[r] = *reinterpret_cast<const half8*>(&xs[row * LDP + ks * 32 + kof]);
        }
#pragma unroll
        for (int t = 0; t < NT; ++t) {
            half8 b = *reinterpret_cast<const half8*>(&Wfrag[(((size_t)t * KS + ks) * 64 + lane) * 8]);
#pragma unroll
            for (int r = 0; r < RW; ++r)
                acc[r][t] = __builtin_amdgcn_mfma_f32_16x16x32_f16(a[r], b, acc[r][t], 0, 0, 0);
        }
    }
#pragma unroll
    for (int r = 0; r < RW; ++r) {
#pragma unroll
        for (int t = 0; t < NT; ++t) {
            int col = t * 16 + (lane & 15);
            float bv = (col < Mh) ? bl[col] : br[col - Mh];
#pragma unroll
            for (int q = 0; q < 4; ++q) {
                int node = node0 + (wave * RW + r) * 16 + (lane >> 4) * 4 + q;
                if (node < n) {
                    float v = acc[r][t][q] + bv;
                    if (col < Mh) yl[(size_t)node * Mh + col] = __float2half(v);
                    else          yr[(size_t)node * Mh + (col - Mh)] = __float2half(v);
                }
            }
        }
    }
}

// 1-edge/thread scatter; cursor pre-initialized to rowstart.
__device__ void scatter_body(int e, const int* __restrict__ src, const int* __restrict__ dst,
                             const float* __restrict__ eattr,
                             int* __restrict__ cursor, int2* __restrict__ es,
                             __half* __restrict__ eah, int E) {
    if (e < E) {
        int d = dst[e];
        int pos = atomicAdd(&cursor[d], 1);
        es[pos] = make_int2(e, src[e]);
        const float4* s4 = (const float4*)&eattr[(size_t)e * 16];
        float4 a = s4[0], b = s4[1], c = s4[2], f = s4[3];
        __half2 h[8];
        h[0] = __float22half2_rn(make_float2(a.x, a.y));
        h[1] = __float22half2_rn(make_float2(a.z, a.w));
        h[2] = __float22half2_rn(make_float2(b.x, b.y));
        h[3] = __float22half2_rn(make_float2(b.z, b.w));
        h[4] = __float22half2_rn(make_float2(c.x, c.y));
        h[5] = __float22half2_rn(make_float2(c.z, c.w));
        h[6] = __float22half2_rn(make_float2(f.x, f.y));
        h[7] = __float22half2_rn(make_float2(f.z, f.w));
        int4* o = (int4*)&eah[(size_t)e * 16];
        o[0] = *(int4*)&h[0];
        o[1] = *(int4*)&h[4];
    }
}

__device__ void dcount_body(int bid, int* h, const int* __restrict__ deg,
                            int* __restrict__ counts, int n) {
    int tid = threadIdx.x;
    h[tid] = 0;
    __syncthreads();
    int base = bid * 4096;
#pragma unroll
    for (int j = 0; j < 16; ++j) {
        int i = base + j * 256 + tid;
        if (i < n) {
            int b = deg[i];
            b = (b > 255) ? 255 : b;
            atomicAdd(&h[b], 1);
        }
    }
    __syncthreads();
    counts[bid * 256 + tid] = h[tid];
}

// FAT kernel: gemm1 || scatter || dcount
__global__ __launch_bounds__(256) void fat_kernel(
    int nbG, int nbS,
    const float* __restrict__ x, const __half* __restrict__ Wf1,
    const float* __restrict__ b1l, const float* __restrict__ b1r,
    __half* __restrict__ A, __half* __restrict__ B, int n,
    const int* __restrict__ src, const int* __restrict__ dst,
    const float* __restrict__ eattr,
    int* __restrict__ cursor, int2* __restrict__ es, __half* __restrict__ eah, int E,
    const int* __restrict__ deg, int* __restrict__ counts) {
    __shared__ __half xs[64 * 136];
    __shared__ int hcnt[256];
    int bid = blockIdx.x;
    if (bid < nbG) {
        gemm_body<128, 64, 64>(bid, xs, x, Wf1, b1l, b1r, A, B, n);
    } else if (bid < nbG + nbS) {
        scatter_body((bid - nbG) * 256 + threadIdx.x, src, dst, eattr, cursor, es, eah, E);
    } else {
        dcount_body(bid - nbG - nbS, hcnt, deg, counts, n);
    }
}

// one 256-thread block: bin totals -> bin starts -> per-block bases
__global__ void dbase_kernel(const int* __restrict__ counts, int* __restrict__ base, int nblk) {
    int b = threadIdx.x;
    int tot = 0;
    for (int k = 0; k < nblk; ++k) tot += counts[k * 256 + b];
    __shared__ int ws[4];
    int lane = b & 63, wid = b >> 6;
    int incl = tot;
#pragma unroll
    for (int off = 1; off < 64; off <<= 1) {
        int t = __shfl_up(incl, off, 64);
        if (lane >= off) incl += t;
    }
    if (lane == 63) ws[wid] = incl;
    __syncthreads();
    int wofs = 0;
    for (int w = 0; w < wid; ++w) wofs += ws[w];
    int acc = wofs + incl - tot;
    for (int k = 0; k < nblk; ++k) {
        base[k * 256 + b] = acc;
        acc += counts[k * 256 + b];
    }
}

__global__ __launch_bounds__(256) void dscatter_block(const int* __restrict__ deg,
                                                      const int* __restrict__ base,
                                                      int* __restrict__ nodeperm, int n) {
    __shared__ int h[256];
    int tid = threadIdx.x;
    h[tid] = 0;
    __syncthreads();
    int bbase = blockIdx.x * 4096;
#pragma unroll
    for (int j = 0; j < 16; ++j) {
        int i = bbase + j * 256 + tid;
        if (i < n) {
            int b = deg[i];
            b = (b > 255) ? 255 : b;
            int r = atomicAdd(&h[b], 1);
            nodeperm[base[blockIdx.x * 256 + b] + r] = i;
        }
    }
}

// standalone gemm for layer 2 (fp16 input)
template <int K, int Mh, int BM>
__global__ __launch_bounds__(256) void gemm_mfma_h(
    const __half* __restrict__ x, const __half* __restrict__ Wfrag,
    const float* __restrict__ bl, const float* __restrict__ br,
    __half* __restrict__ yl, __half* __restrict__ yr, int n) {
    __shared__ __half xs[BM * (K + 8)];
    gemm_body_h<K, Mh, BM>(blockIdx.x, xs, x, Wfrag, bl, br, yl, yr, n);
}

// y[n,M] = x[n,K] @ W[K,M] + b ; fp16 input, fp32 math (final head)
template <int K, int M, int NPB>
__global__ void linear_kernel(const __half* __restrict__ x, const float* __restrict__ W,
                              const float* __restrict__ b, float* __restrict__ y, int n) {
    __shared__ float sx[NPB * K];
    int tid = threadIdx.x;
    int node0 = blockIdx.x * NPB;
    for (int i = tid; i < NPB * K; i += NPB * M) {
        int nn = node0 + i / K;
        sx[i] = (nn < n) ? __half2float(x[(size_t)nn * K + (i % K)]) : 0.f;
    }
    __syncthreads();
    int ln = tid / M, m = tid % M;
    int node = node0 + ln;
    if (node >= n) return;
    float acc = b[m];
#pragma unroll
    for (int k = 0; k < K; ++k) acc = fmaf(sx[ln * K + k], W[k * M + m], acc);
    y[(size_t)node * M + m] = acc;
}

// FUSED edge-logit + softmax + aggregate, 3-stage software pipeline:
// prefetch es[i+2] || load eah/xl[i+1] || compute[i].
template <int H, int C>
__global__ __launch_bounds__(256) void fused_edge_agg(
    const int* __restrict__ rowstart, const int2* __restrict__ es,
    const __half* __restrict__ eah, const int* __restrict__ nodeperm,
    const float* __restrict__ We,    // [16, HC]
    const float* __restrict__ att,   // [HC]
    const __half* __restrict__ xl, const __half* __restrict__ xr,
    const float* __restrict__ bias, __half* __restrict__ out, int n) {
    constexpr int HC = H * C;
    constexpr int LPN = HC / 2;
    constexpr int NPW = 64 / LPN;
    int gt = blockIdx.x * blockDim.x + threadIdx.x;
    int wave = gt >> 6;
    int lane = threadIdx.x & 63;
    int sub = lane / LPN;
    int j = lane % LPN;
    int ch0 = 2 * j;
    int slot = wave * NPW + sub;
    if (slot >= n) return;
    int node = nodeperm[slot];
    __half2 wh[16];
#pragma unroll
    for (int k = 0; k < 16; ++k) wh[k] = __float22half2_rn(*(const float2*)&We[k * HC + ch0]);
    float2 a2 = *(const float2*)&att[ch0];
    float2 xr2 = __half22float2(*(const __half2*)&xr[(size_t)node * HC + ch0]);
    int beg = rowstart[node], end = rowstart[node + 1];
    float denom = 0.f, acc0 = 0.f, acc1 = 0.f;

    auto gemv = [&](const float4& r0, const float4& r1, const __half2& xlh,
                    float& m0, float& m1, float2& xlf) {
        const __half2* h0 = (const __half2*)&r0;
        const __half2* h1 = (const __half2*)&r1;
        __half2 p0 = __hmul2(__low2half2(h0[0]), wh[0]);
        __half2 p1 = __hmul2(__high2half2(h0[0]), wh[1]);
        p0 = __hfma2(__low2half2(h0[1]), wh[2], p0);
        p1 = __hfma2(__high2half2(h0[1]), wh[3], p1);
        p0 = __hfma2(__low2half2(h0[2]), wh[4], p0);
        p1 = __hfma2(__high2half2(h0[2]), wh[5], p1);
        p0 = __hfma2(__low2half2(h0[3]), wh[6], p0);
        p1 = __hfma2(__high2half2(h0[3]), wh[7], p1);
        p0 = __hfma2(__low2half2(h1[0]), wh[8], p0);
        p1 = __hfma2(__high2half2(h1[0]), wh[9], p1);
        p0 = __hfma2(__low2half2(h1[1]), wh[10], p0);
        p1 = __hfma2(__high2half2(h1[1]), wh[11], p1);
        p0 = __hfma2(__low2half2(h1[2]), wh[12], p0);
        p1 = __hfma2(__high2half2(h1[2]), wh[13], p1);
        p0 = __hfma2(__low2half2(h1[3]), wh[14], p0);
        p1 = __hfma2(__high2half2(h1[3]), wh[15], p1);
        float2 mf = __half22float2(__hadd2(p0, p1));
        xlf = __half22float2(xlh);
        m0 = xlf.x + xr2.x + mf.x;
        m1 = xlf.y + xr2.y + mf.y;
    };
    auto logit = [&](float m0, float m1) -> float {
        m0 = (m0 > 0.f) ? m0 : 0.2f * m0;
        m1 = (m1 > 0.f) ? m1 : 0.2f * m1;
        float v = m0 * a2.x + m1 * a2.y;
#pragma unroll
        for (int msk = 1; msk < 16; msk <<= 1) v += __shfl_xor(v, msk, 64);
        return v;
    };
    auto accum = [&](const float4& r0a, const float4& r1a, const __half2& xh0,
                     const float4& r0b, const float4& r1b, const __half2& xh1) {
        float m0a, m1a, m0b, m1b;
        float2 xla, xlb;
        gemv(r0a, r1a, xh0, m0a, m1a, xla);
        gemv(r0b, r1b, xh1, m0b, m1b, xlb);
        float wa = __expf(logit(m0a, m1a));
        float wb = __expf(logit(m0b, m1b));
        denom += wa + wb;
        acc0 = fmaf(xla.x, wa, acc0);
        acc1 = fmaf(xla.y, wa, acc1);
        acc0 = fmaf(xlb.x, wb, acc0);
        acc1 = fmaf(xlb.y, wb, acc1);
    };

    int pp = beg;
    // --- 3-stage pipeline over edge pairs ---
    if (pp + 2 <= end) {
        // stage regs: cur data (r*,xh*), next es pair (f0,f1)
        int2 e0 = es[pp], e1 = es[pp + 1];
        const float4* qa = (const float4*)&eah[(size_t)e0.x * 16];
        const float4* qb = (const float4*)&eah[(size_t)e1.x * 16];
        float4 r0a = qa[0], r1a = qa[1], r0b = qb[0], r1b = qb[1];
        __half2 xh0 = *(const __half2*)&xl[(size_t)e0.y * HC + ch0];
        __half2 xh1 = *(const __half2*)&xl[(size_t)e1.y * HC + ch0];
        int2 f0, f1;
        bool have_next = (pp + 4 <= end);
        if (have_next) {
            f0 = es[pp + 2];
            f1 = es[pp + 3];
        }
        for (; pp + 4 <= end; pp += 2) {
            // load next pair's data (from f0/f1, issued before compute)
            const float4* na = (const float4*)&eah[(size_t)f0.x * 16];
            const float4* nb = (const float4*)&eah[(size_t)f1.x * 16];
            float4 s0a = na[0], s1a = na[1], s0b = nb[0], s1b = nb[1];
            __half2 yh0 = *(const __half2*)&xl[(size_t)f0.y * HC + ch0];
            __half2 yh1 = *(const __half2*)&xl[(size_t)f1.y * HC + ch0];
            // prefetch next-next es pair
            int2 g0, g1;
            bool have_nn = (pp + 6 <= end);
            if (have_nn) {
                g0 = es[pp + 4];
                g1 = es[pp + 5];
            }
            // compute current while loads are in flight
            accum(r0a, r1a, xh0, r0b, r1b, xh1);
            // rotate
            r0a = s0a; r1a = s1a; r0b = s0b; r1b = s1b;
            xh0 = yh0; xh1 = yh1;
            f0 = g0; f1 = g1;
        }
        // drain last full pair
        accum(r0a, r1a, xh0, r0b, r1b, xh1);
        pp += 2;
    }
    // tail (0 or 1 edge)
    if (pp < end) {
        int2 ea = es[pp];
        const float4* qa = (const float4*)&eah[(size_t)ea.x * 16];
        float4 r0a = qa[0], r1a = qa[1];
        __half2 xh0 = *(const __half2*)&xl[(size_t)ea.y * HC + ch0];
        float m0a, m1a;
        float2 xla;
        gemv(r0a, r1a, xh0, m0a, m1a, xla);
        float wa = __expf(logit(m0a, m1a));
        denom += wa;
        acc0 = fmaf(xla.x, wa, acc0);
        acc1 = fmaf(xla.y, wa, acc1);
    }
    float2 b2 = *(const float2*)&bias[ch0];
    float inv = 1.f / (denom + 1e-16f);
    float o0 = acc0 * inv + b2.x;
    float o1 = acc1 * inv + b2.y;
    o0 = (o0 > 0.f) ? o0 : __expf(o0) - 1.f;
    o1 = (o1 > 0.f) ? o1 : __expf(o1) - 1.f;
    *(__half2*)&out[(size_t)node * HC + ch0] = __float22half2_rn(make_float2(o0, o1));
}

extern "C" void kernel_launch(void* const* d_in, const int* in_sizes, int n_in,
                              void* d_out, int out_size, void* d_ws, size_t ws_size,
                              hipStream_t stream) {
    const float* x     = (const float*)d_in[0];
    const int*   eidx  = (const int*)d_in[1];
    const float* eattr = (const float*)d_in[2];
    const float* W1l   = (const float*)d_in[3];
    const float* b1l   = (const float*)d_in[4];
    const float* W1r   = (const float*)d_in[5];
    const float* b1r   = (const float*)d_in[6];
    const float* W1e   = (const float*)d_in[7];
    const float* att1  = (const float*)d_in[8];
    const float* bias1 = (const float*)d_in[9];
    const float* W2l   = (const float*)d_in[10];
    const float* b2l   = (const float*)d_in[11];
    const float* W2r   = (const float*)d_in[12];
    const float* b2r   = (const float*)d_in[13];
    const float* W2e   = (const float*)d_in[14];
    const float* att2  = (const float*)d_in[15];
    const float* bias2 = (const float*)d_in[16];
    const float* Wlin  = (const float*)d_in[17];
    const float* blin  = (const float*)d_in[18];

    const int N = in_sizes[0] / 128;
    const int E = in_sizes[1] / 2;
    const int* src = eidx;
    const int* dst = eidx + E;
    const int NB_DC = (N + 4095) / 4096;

    char* p = (char*)d_ws;
    auto take = [&](size_t bytes) {
        char* r = p;
        p += (bytes + 255) & ~(size_t)255;
        return r;
    };
    int*    deg      = (int*)take((size_t)N * sizeof(int));
    char*   zero_end = p;
    int*    cursor   = (int*)take((size_t)N * sizeof(int));
    int*    rowstart = (int*)take((size_t)(N + 1) * sizeof(int));
    int*    bsum     = (int*)take(256 * sizeof(int));
    int*    counts   = (int*)take((size_t)(NB_DC + 1) * 256 * sizeof(int));
    int*    dbase    = (int*)take((size_t)(NB_DC + 1) * 256 * sizeof(int));
    int*    nodeperm = (int*)take((size_t)N * sizeof(int));
    int2*   es       = (int2*)take((size_t)E * sizeof(int2));
    __half* eah      = (__half*)take((size_t)E * 16 * sizeof(__half));
    __half* A        = (__half*)take((size_t)N * 64 * sizeof(__half));
    __half* B        = (__half*)take((size_t)N * 64 * sizeof(__half));
    __half* Chalf    = (__half*)take((size_t)N * 64 * sizeof(__half));
    __half* Wf1      = (__half*)take((size_t)128 * 128 * sizeof(__half));
    __half* Wf2      = (__half*)take((size_t)64 * 64 * sizeof(__half));

    // ---- CSR build + weight repack ----
    (void)hipMemsetAsync(deg, 0, (size_t)(zero_end - (char*)deg), stream);
    hist_kernel<<<(E + 255) / 256, 256, 0, stream>>>(dst, deg, E);
    {
        int nb = (N + 1023) / 1024;
        scan_part<<<nb, 256, 0, stream>>>(deg, bsum, N);
        scan_mid<<<1, 128, 0, stream>>>(bsum, rowstart, nb, N);
        scan_fin<<<nb, 256, 0, stream>>>(deg, bsum, rowstart, cursor, N);
    }
    wprep_both<<<80, 256, 0, stream>>>(W1l, W1r, Wf1, W2l, W2r, Wf2);

    // ---- FAT: gemm1 || scatter || dcount ----
    {
        int nbG = (N + 63) / 64;
        int nbS = (E + 255) / 256;
        fat_kernel<<<nbG + nbS + NB_DC, 256, 0, stream>>>(
            nbG, nbS, x, Wf1, b1l, b1r, A, B, N, src, dst, eattr, cursor, es, eah, E,
            deg, counts);
    }
    dbase_kernel<<<1, 256, 0, stream>>>(counts, dbase, NB_DC);
    dscatter_block<<<NB_DC, 256, 0, stream>>>(deg, dbase, nodeperm, N);

    // ---- Layer 1: H=2, C=32 (2 nodes/wave) ----
    {
        long waves = (N + 1) / 2;
        fused_edge_agg<2, 32><<<(int)((waves * 64 + 255) / 256), 256, 0, stream>>>(
            rowstart, es, eah, nodeperm, W1e, att1, A, B, bias1, Chalf, N);
    }

    // ---- Layer 2: H=1, C=32 (4 nodes/wave) ----
    gemm_mfma_h<64, 32, 128><<<(N + 127) / 128, 256, 0, stream>>>(Chalf, Wf2, b2l, b2r, A, B, N);
    {
        long waves = (N + 3) / 4;
        fused_edge_agg<1, 32><<<(int)((waves * 64 + 255) / 256), 256, 0, stream>>>(
            rowstart, es, eah, nodeperm, W2e, att2, A, B, bias2, Chalf, N);
    }

    // ---- Final linear ----
    linear_kernel<32, 32, 8><<<(N + 7) / 8, 256, 0, stream>>>(Chalf, Wlin, blin, (float*)d_out, N);
}

// Round 21
// 394.019 us; speedup vs baseline: 1.0600x; 1.0232x over previous
//
#include <hip/hip_runtime.h>
#include <hip/hip_fp16.h>
#include <cstdint>
#include <cstddef>

// ---------------------------------------------------------------------------
// GATv2 x2 + linear head on MI355X.  (best measured config — round 18)
// hist -> 3-phase scan (writes rowstart+cursor) -> wprep -> FAT{gemm1 ||
// scatter(es int2 + eah fp16) || dcount} -> dbase/dscatter (degree binning)
// -> fused L1 -> gemm2 -> fused L2 -> linear. Degree-ordered nodes; packed
// fp16 GEMV; MFMA GEMMs. No float atomics.
// ---------------------------------------------------------------------------

typedef _Float16 half8 __attribute__((ext_vector_type(8)));
typedef float f32x4 __attribute__((ext_vector_type(4)));

__global__ void hist_kernel(const int* __restrict__ dst, int* __restrict__ deg, int E) {
    int e = blockIdx.x * blockDim.x + threadIdx.x;
    if (e < E) atomicAdd(&deg[dst[e]], 1);
}

// ---- 3-phase exclusive scan of deg[0..n) -> rowstart[0..n] (+cursor) ----
__global__ void scan_part(const int* __restrict__ deg, int* __restrict__ bsum, int n) {
    int tid = threadIdx.x;
    int base = blockIdx.x * 1024 + tid * 4;
    int s = 0;
#pragma unroll
    for (int j = 0; j < 4; ++j) {
        int i = base + j;
        if (i < n) s += deg[i];
    }
#pragma unroll
    for (int off = 1; off < 64; off <<= 1) s += __shfl_xor(s, off, 64);
    __shared__ int ws[4];
    if ((tid & 63) == 0) ws[tid >> 6] = s;
    __syncthreads();
    if (tid == 0) bsum[blockIdx.x] = ws[0] + ws[1] + ws[2] + ws[3];
}

__global__ void scan_mid(int* __restrict__ bsum, int* __restrict__ rowstart, int nb, int n) {
    int tid = threadIdx.x;
    int v = (tid < nb) ? bsum[tid] : 0;
    int incl = v;
#pragma unroll
    for (int off = 1; off < 64; off <<= 1) {
        int t = __shfl_up(incl, off, 64);
        if ((tid & 63) >= off) incl += t;
    }
    __shared__ int w0;
    if (tid == 63) w0 = incl;
    __syncthreads();
    if (tid >= 64) incl += w0;
    if (tid < nb) bsum[tid] = incl - v;
    if (tid == nb - 1) rowstart[n] = incl;
}

__global__ void scan_fin(const int* __restrict__ deg, const int* __restrict__ bsum,
                         int* __restrict__ rowstart, int* __restrict__ cursor, int n) {
    int tid = threadIdx.x;
    int lane = tid & 63, wid = tid >> 6;
    int base = blockIdx.x * 1024 + tid * 4;
    int v[4];
    int s = 0;
#pragma unroll
    for (int j = 0; j < 4; ++j) {
        int i = base + j;
        v[j] = (i < n) ? deg[i] : 0;
        s += v[j];
    }
    int incl = s;
#pragma unroll
    for (int off = 1; off < 64; off <<= 1) {
        int t = __shfl_up(incl, off, 64);
        if (lane >= off) incl += t;
    }
    __shared__ int ws[4];
    if (lane == 63) ws[wid] = incl;
    __syncthreads();
    int wofs = 0;
    for (int w2 = 0; w2 < wid; ++w2) wofs += ws[w2];
    int acc = bsum[blockIdx.x] + wofs + (incl - s);
#pragma unroll
    for (int j = 0; j < 4; ++j) {
        int i = base + j;
        if (i < n) {
            rowstart[i] = acc;
            cursor[i] = acc;
        }
        acc += v[j];
    }
}

// Repack [Wl|Wr] into MFMA B-fragment order; two weight sets in one launch.
template <int K, int Mh>
__device__ void wprep_body(int i, const float* __restrict__ Wl, const float* __restrict__ Wr,
                           __half* __restrict__ Wfrag) {
    constexpr int KS = K / 32;
    if (i >= K * 2 * Mh) return;
    int j = i & 7;
    int lane = (i >> 3) & 63;
    int rest = i >> 9;
    int ks = rest % KS;
    int nt = rest / KS;
    int k = ks * 32 + ((lane >> 4) & 3) * 8 + j;
    int col = nt * 16 + (lane & 15);
    float v = (col < Mh) ? Wl[k * Mh + col] : Wr[k * Mh + (col - Mh)];
    Wfrag[i] = __float2half(v);
}

__global__ void wprep_both(const float* W1l, const float* W1r, __half* Wf1,
                           const float* W2l, const float* W2r, __half* Wf2) {
    int bid = blockIdx.x;
    int tid = threadIdx.x;
    if (bid < 64) wprep_body<128, 64>(bid * 256 + tid, W1l, W1r, Wf1);
    else          wprep_body<64, 32>((bid - 64) * 256 + tid, W2l, W2r, Wf2);
}

// ---- MFMA dual GEMM body (fp32 input; shared by fat kernel) ----
template <int K, int Mh, int BM>
__device__ void gemm_body(int bid, __half* xs, const float* __restrict__ x,
                          const __half* __restrict__ Wfrag, const float* __restrict__ bl,
                          const float* __restrict__ br, __half* __restrict__ yl,
                          __half* __restrict__ yr, int n) {
    constexpr int KS = K / 32;
    constexpr int NT = (2 * Mh) / 16;
    constexpr int RW = BM / 64;
    constexpr int LDP = K + 8;
    int tid = threadIdx.x;
    int lane = tid & 63;
    int wave = tid >> 6;
    int node0 = bid * BM;
    constexpr int ITER = (BM * K) / (256 * 4);
#pragma unroll
    for (int it = 0; it < ITER; ++it) {
        int base = (it * 256 + tid) * 4;
        int row = base / K, kk = base % K;
        float4 v = make_float4(0.f, 0.f, 0.f, 0.f);
        if (node0 + row < n) v = *(const float4*)&x[(size_t)(node0 + row) * K + kk];
        __half2* d = (__half2*)&xs[row * LDP + kk];
        d[0] = __float22half2_rn(make_float2(v.x, v.y));
        d[1] = __float22half2_rn(make_float2(v.z, v.w));
    }
    __syncthreads();
    f32x4 acc[RW][NT];
#pragma unroll
    for (int r = 0; r < RW; ++r)
#pragma unroll
        for (int t = 0; t < NT; ++t) {
            f32x4 z = {0.f, 0.f, 0.f, 0.f};
            acc[r][t] = z;
        }
    int r0 = lane & 15, kof = (lane >> 4) * 8;
#pragma unroll
    for (int ks = 0; ks < KS; ++ks) {
        half8 a[RW];
#pragma unroll
        for (int r = 0; r < RW; ++r) {
            int row = (wave * RW + r) * 16 + r0;
            a[r] = *reinterpret_cast<const half8*>(&xs[row * LDP + ks * 32 + kof]);
        }
#pragma unroll
        for (int t = 0; t < NT; ++t) {
            half8 b = *reinterpret_cast<const half8*>(&Wfrag[(((size_t)t * KS + ks) * 64 + lane) * 8]);
#pragma unroll
            for (int r = 0; r < RW; ++r)
                acc[r][t] = __builtin_amdgcn_mfma_f32_16x16x32_f16(a[r], b, acc[r][t], 0, 0, 0);
        }
    }
#pragma unroll
    for (int r = 0; r < RW; ++r) {
#pragma unroll
        for (int t = 0; t < NT; ++t) {
            int col = t * 16 + (lane & 15);
            float bv = (col < Mh) ? bl[col] : br[col - Mh];
#pragma unroll
            for (int q = 0; q < 4; ++q) {
                int node = node0 + (wave * RW + r) * 16 + (lane >> 4) * 4 + q;
                if (node < n) {
                    float v = acc[r][t][q] + bv;
                    if (col < Mh) yl[(size_t)node * Mh + col] = __float2half(v);
                    else          yr[(size_t)node * Mh + (col - Mh)] = __float2half(v);
                }
            }
        }
    }
}

// fp16-input gemm body for layer 2
template <int K, int Mh, int BM>
__device__ void gemm_body_h(int bid, __half* xs, const __half* __restrict__ x,
                            const __half* __restrict__ Wfrag, const float* __restrict__ bl,
                            const float* __restrict__ br, __half* __restrict__ yl,
                            __half* __restrict__ yr, int n) {
    constexpr int KS = K / 32;
    constexpr int NT = (2 * Mh) / 16;
    constexpr int RW = BM / 64;
    constexpr int LDP = K + 8;
    int tid = threadIdx.x;
    int lane = tid & 63;
    int wave = tid >> 6;
    int node0 = bid * BM;
    constexpr int ITER = (BM * K) / (256 * 8);
#pragma unroll
    for (int it = 0; it < ITER; ++it) {
        int base = (it * 256 + tid) * 8;
        int row = base / K, kk = base % K;
        int4 v = make_int4(0, 0, 0, 0);
        if (node0 + row < n) v = *(const int4*)&x[(size_t)(node0 + row) * K + kk];
        *(int4*)&xs[row * LDP + kk] = v;
    }
    __syncthreads();
    f32x4 acc[RW][NT];
#pragma unroll
    for (int r = 0; r < RW; ++r)
#pragma unroll
        for (int t = 0; t < NT; ++t) {
            f32x4 z = {0.f, 0.f, 0.f, 0.f};
            acc[r][t] = z;
        }
    int r0 = lane & 15, kof = (lane >> 4) * 8;
#pragma unroll
    for (int ks = 0; ks < KS; ++ks) {
        half8 a[RW];
#pragma unroll
        for (int r = 0; r < RW; ++r) {
            int row = (wave * RW + r) * 16 + r0;
            a[r] = *reinterpret_cast<const half8*>(&xs[row * LDP + ks * 32 + kof]);
        }
#pragma unroll
        for (int t = 0; t < NT; ++t) {
            half8 b = *reinterpret_cast<const half8*>(&Wfrag[(((size_t)t * KS + ks) * 64 + lane) * 8]);
#pragma unroll
            for (int r = 0; r < RW; ++r)
                acc[r][t] = __builtin_amdgcn_mfma_f32_16x16x32_f16(a[r], b, acc[r][t], 0, 0, 0);
        }
    }
#pragma unroll
    for (int r = 0; r < RW; ++r) {
#pragma unroll
        for (int t = 0; t < NT; ++t) {
            int col = t * 16 + (lane & 15);
            float bv = (col < Mh) ? bl[col] : br[col - Mh];
#pragma unroll
            for (int q = 0; q < 4; ++q) {
                int node = node0 + (wave * RW + r) * 16 + (lane >> 4) * 4 + q;
                if (node < n) {
                    float v = acc[r][t][q] + bv;
                    if (col < Mh) yl[(size_t)node * Mh + col] = __float2half(v);
                    else          yr[(size_t)node * Mh + (col - Mh)] = __float2half(v);
                }
            }
        }
    }
}

// 1-edge/thread scatter; cursor pre-initialized to rowstart (no extra gather).
__device__ void scatter_body(int e, const int* __restrict__ src, const int* __restrict__ dst,
                             const float* __restrict__ eattr,
                             int* __restrict__ cursor, int2* __restrict__ es,
                             __half* __restrict__ eah, int E) {
    if (e < E) {
        int d = dst[e];
        int pos = atomicAdd(&cursor[d], 1);
        es[pos] = make_int2(e, src[e]);
        const float4* s4 = (const float4*)&eattr[(size_t)e * 16];
        float4 a = s4[0], b = s4[1], c = s4[2], f = s4[3];
        __half2 h[8];
        h[0] = __float22half2_rn(make_float2(a.x, a.y));
        h[1] = __float22half2_rn(make_float2(a.z, a.w));
        h[2] = __float22half2_rn(make_float2(b.x, b.y));
        h[3] = __float22half2_rn(make_float2(b.z, b.w));
        h[4] = __float22half2_rn(make_float2(c.x, c.y));
        h[5] = __float22half2_rn(make_float2(c.z, c.w));
        h[6] = __float22half2_rn(make_float2(f.x, f.y));
        h[7] = __float22half2_rn(make_float2(f.z, f.w));
        int4* o = (int4*)&eah[(size_t)e * 16];
        o[0] = *(int4*)&h[0];
        o[1] = *(int4*)&h[4];
    }
}

__device__ void dcount_body(int bid, int* h, const int* __restrict__ deg,
                            int* __restrict__ counts, int n) {
    int tid = threadIdx.x;
    h[tid] = 0;
    __syncthreads();
    int base = bid * 4096;
#pragma unroll
    for (int j = 0; j < 16; ++j) {
        int i = base + j * 256 + tid;
        if (i < n) {
            int b = deg[i];
            b = (b > 255) ? 255 : b;
            atomicAdd(&h[b], 1);
        }
    }
    __syncthreads();
    counts[bid * 256 + tid] = h[tid];
}

// FAT kernel: gemm1 (blocks [0,nbG)) || scatter ([nbG,nbG+nbS)) || dcount (rest)
__global__ __launch_bounds__(256) void fat_kernel(
    int nbG, int nbS,
    const float* __restrict__ x, const __half* __restrict__ Wf1,
    const float* __restrict__ b1l, const float* __restrict__ b1r,
    __half* __restrict__ A, __half* __restrict__ B, int n,
    const int* __restrict__ src, const int* __restrict__ dst,
    const float* __restrict__ eattr,
    int* __restrict__ cursor, int2* __restrict__ es, __half* __restrict__ eah, int E,
    const int* __restrict__ deg, int* __restrict__ counts) {
    __shared__ __half xs[64 * 136];
    __shared__ int hcnt[256];
    int bid = blockIdx.x;
    if (bid < nbG) {
        gemm_body<128, 64, 64>(bid, xs, x, Wf1, b1l, b1r, A, B, n);
    } else if (bid < nbG + nbS) {
        scatter_body((bid - nbG) * 256 + threadIdx.x, src, dst, eattr, cursor, es, eah, E);
    } else {
        dcount_body(bid - nbG - nbS, hcnt, deg, counts, n);
    }
}

// one 256-thread block: bin totals -> bin starts -> per-block bases
__global__ void dbase_kernel(const int* __restrict__ counts, int* __restrict__ base, int nblk) {
    int b = threadIdx.x;
    int tot = 0;
    for (int k = 0; k < nblk; ++k) tot += counts[k * 256 + b];
    __shared__ int ws[4];
    int lane = b & 63, wid = b >> 6;
    int incl = tot;
#pragma unroll
    for (int off = 1; off < 64; off <<= 1) {
        int t = __shfl_up(incl, off, 64);
        if (lane >= off) incl += t;
    }
    if (lane == 63) ws[wid] = incl;
    __syncthreads();
    int wofs = 0;
    for (int w = 0; w < wid; ++w) wofs += ws[w];
    int acc = wofs + incl - tot;
    for (int k = 0; k < nblk; ++k) {
        base[k * 256 + b] = acc;
        acc += counts[k * 256 + b];
    }
}

__global__ __launch_bounds__(256) void dscatter_block(const int* __restrict__ deg,
                                                      const int* __restrict__ base,
                                                      int* __restrict__ nodeperm, int n) {
    __shared__ int h[256];
    int tid = threadIdx.x;
    h[tid] = 0;
    __syncthreads();
    int bbase = blockIdx.x * 4096;
#pragma unroll
    for (int j = 0; j < 16; ++j) {
        int i = bbase + j * 256 + tid;
        if (i < n) {
            int b = deg[i];
            b = (b > 255) ? 255 : b;
            int r = atomicAdd(&h[b], 1);
            nodeperm[base[blockIdx.x * 256 + b] + r] = i;
        }
    }
}

// standalone gemm for layer 2 (fp16 input)
template <int K, int Mh, int BM>
__global__ __launch_bounds__(256) void gemm_mfma_h(
    const __half* __restrict__ x, const __half* __restrict__ Wfrag,
    const float* __restrict__ bl, const float* __restrict__ br,
    __half* __restrict__ yl, __half* __restrict__ yr, int n) {
    __shared__ __half xs[BM * (K + 8)];
    gemm_body_h<K, Mh, BM>(blockIdx.x, xs, x, Wfrag, bl, br, yl, yr, n);
}

// y[n,M] = x[n,K] @ W[K,M] + b ; fp16 input, fp32 math (final head)
template <int K, int M, int NPB>
__global__ void linear_kernel(const __half* __restrict__ x, const float* __restrict__ W,
                              const float* __restrict__ b, float* __restrict__ y, int n) {
    __shared__ float sx[NPB * K];
    int tid = threadIdx.x;
    int node0 = blockIdx.x * NPB;
    for (int i = tid; i < NPB * K; i += NPB * M) {
        int nn = node0 + i / K;
        sx[i] = (nn < n) ? __half2float(x[(size_t)nn * K + (i % K)]) : 0.f;
    }
    __syncthreads();
    int ln = tid / M, m = tid % M;
    int node = node0 + ln;
    if (node >= n) return;
    float acc = b[m];
#pragma unroll
    for (int k = 0; k < K; ++k) acc = fmaf(sx[ln * K + k], W[k * M + m], acc);
    y[(size_t)node * M + m] = acc;
}

// FUSED edge-logit + softmax + aggregate (round-12 form, fp16 output).
template <int H, int C>
__global__ __launch_bounds__(256) void fused_edge_agg(
    const int* __restrict__ rowstart, const int2* __restrict__ es,
    const __half* __restrict__ eah, const int* __restrict__ nodeperm,
    const float* __restrict__ We,    // [16, HC]
    const float* __restrict__ att,   // [HC]
    const __half* __restrict__ xl, const __half* __restrict__ xr,
    const float* __restrict__ bias, __half* __restrict__ out, int n) {
    constexpr int HC = H * C;
    constexpr int LPN = HC / 2;
    constexpr int NPW = 64 / LPN;
    int gt = blockIdx.x * blockDim.x + threadIdx.x;
    int wave = gt >> 6;
    int lane = threadIdx.x & 63;
    int sub = lane / LPN;
    int j = lane % LPN;
    int ch0 = 2 * j;
    int slot = wave * NPW + sub;
    if (slot >= n) return;
    int node = nodeperm[slot];
    __half2 wh[16];
#pragma unroll
    for (int k = 0; k < 16; ++k) wh[k] = __float22half2_rn(*(const float2*)&We[k * HC + ch0]);
    float2 a2 = *(const float2*)&att[ch0];
    float2 xr2 = __half22float2(*(const __half2*)&xr[(size_t)node * HC + ch0]);
    int beg = rowstart[node], end = rowstart[node + 1];
    float denom = 0.f, acc0 = 0.f, acc1 = 0.f;

    auto gemv = [&](const float4& r0, const float4& r1, const __half2& xlh,
                    float& m0, float& m1, float2& xlf) {
        const __half2* h0 = (const __half2*)&r0;
        const __half2* h1 = (const __half2*)&r1;
        __half2 p0 = __hmul2(__low2half2(h0[0]), wh[0]);
        __half2 p1 = __hmul2(__high2half2(h0[0]), wh[1]);
        p0 = __hfma2(__low2half2(h0[1]), wh[2], p0);
        p1 = __hfma2(__high2half2(h0[1]), wh[3], p1);
        p0 = __hfma2(__low2half2(h0[2]), wh[4], p0);
        p1 = __hfma2(__high2half2(h0[2]), wh[5], p1);
        p0 = __hfma2(__low2half2(h0[3]), wh[6], p0);
        p1 = __hfma2(__high2half2(h0[3]), wh[7], p1);
        p0 = __hfma2(__low2half2(h1[0]), wh[8], p0);
        p1 = __hfma2(__high2half2(h1[0]), wh[9], p1);
        p0 = __hfma2(__low2half2(h1[1]), wh[10], p0);
        p1 = __hfma2(__high2half2(h1[1]), wh[11], p1);
        p0 = __hfma2(__low2half2(h1[2]), wh[12], p0);
        p1 = __hfma2(__high2half2(h1[2]), wh[13], p1);
        p0 = __hfma2(__low2half2(h1[3]), wh[14], p0);
        p1 = __hfma2(__high2half2(h1[3]), wh[15], p1);
        float2 mf = __half22float2(__hadd2(p0, p1));
        xlf = __half22float2(xlh);
        m0 = xlf.x + xr2.x + mf.x;
        m1 = xlf.y + xr2.y + mf.y;
    };
    auto logit = [&](float m0, float m1) -> float {
        m0 = (m0 > 0.f) ? m0 : 0.2f * m0;
        m1 = (m1 > 0.f) ? m1 : 0.2f * m1;
        float v = m0 * a2.x + m1 * a2.y;
#pragma unroll
        for (int msk = 1; msk < 16; msk <<= 1) v += __shfl_xor(v, msk, 64);
        return v;
    };

    int pp = beg;
    for (; pp + 2 <= end; pp += 2) {
        int2 ea = es[pp];
        int2 eb = es[pp + 1];
        const float4* qa = (const float4*)&eah[(size_t)ea.x * 16];
        const float4* qb = (const float4*)&eah[(size_t)eb.x * 16];
        float4 r0a = qa[0], r1a = qa[1];
        float4 r0b = qb[0], r1b = qb[1];
        __half2 xh0 = *(const __half2*)&xl[(size_t)ea.y * HC + ch0];
        __half2 xh1 = *(const __half2*)&xl[(size_t)eb.y * HC + ch0];
        float m0a, m1a, m0b, m1b;
        float2 xla, xlb;
        gemv(r0a, r1a, xh0, m0a, m1a, xla);
        gemv(r0b, r1b, xh1, m0b, m1b, xlb);
        float wa = __expf(logit(m0a, m1a));
        float wb = __expf(logit(m0b, m1b));
        denom += wa + wb;
        acc0 = fmaf(xla.x, wa, acc0);
        acc1 = fmaf(xla.y, wa, acc1);
        acc0 = fmaf(xlb.x, wb, acc0);
        acc1 = fmaf(xlb.y, wb, acc1);
    }
    if (pp < end) {
        int2 ea = es[pp];
        const float4* qa = (const float4*)&eah[(size_t)ea.x * 16];
        float4 r0a = qa[0], r1a = qa[1];
        __half2 xh0 = *(const __half2*)&xl[(size_t)ea.y * HC + ch0];
        float m0a, m1a;
        float2 xla;
        gemv(r0a, r1a, xh0, m0a, m1a, xla);
        float wa = __expf(logit(m0a, m1a));
        denom += wa;
        acc0 = fmaf(xla.x, wa, acc0);
        acc1 = fmaf(xla.y, wa, acc1);
    }
    float2 b2 = *(const float2*)&bias[ch0];
    float inv = 1.f / (denom + 1e-16f);
    float o0 = acc0 * inv + b2.x;
    float o1 = acc1 * inv + b2.y;
    o0 = (o0 > 0.f) ? o0 : __expf(o0) - 1.f;
    o1 = (o1 > 0.f) ? o1 : __expf(o1) - 1.f;
    *(__half2*)&out[(size_t)node * HC + ch0] = __float22half2_rn(make_float2(o0, o1));
}

extern "C" void kernel_launch(void* const* d_in, const int* in_sizes, int n_in,
                              void* d_out, int out_size, void* d_ws, size_t ws_size,
                              hipStream_t stream) {
    const float* x     = (const float*)d_in[0];
    const int*   eidx  = (const int*)d_in[1];
    const float* eattr = (const float*)d_in[2];
    const float* W1l   = (const float*)d_in[3];
    const float* b1l   = (const float*)d_in[4];
    const float* W1r   = (const float*)d_in[5];
    const float* b1r   = (const float*)d_in[6];
    const float* W1e   = (const float*)d_in[7];
    const float* att1  = (const float*)d_in[8];
    const float* bias1 = (const float*)d_in[9];
    const float* W2l   = (const float*)d_in[10];
    const float* b2l   = (const float*)d_in[11];
    const float* W2r   = (const float*)d_in[12];
    const float* b2r   = (const float*)d_in[13];
    const float* W2e   = (const float*)d_in[14];
    const float* att2  = (const float*)d_in[15];
    const float* bias2 = (const float*)d_in[16];
    const float* Wlin  = (const float*)d_in[17];
    const float* blin  = (const float*)d_in[18];

    const int N = in_sizes[0] / 128;
    const int E = in_sizes[1] / 2;
    const int* src = eidx;
    const int* dst = eidx + E;
    const int NB_DC = (N + 4095) / 4096;

    char* p = (char*)d_ws;
    auto take = [&](size_t bytes) {
        char* r = p;
        p += (bytes + 255) & ~(size_t)255;
        return r;
    };
    int*    deg      = (int*)take((size_t)N * sizeof(int));
    char*   zero_end = p;
    int*    cursor   = (int*)take((size_t)N * sizeof(int));
    int*    rowstart = (int*)take((size_t)(N + 1) * sizeof(int));
    int*    bsum     = (int*)take(256 * sizeof(int));
    int*    counts   = (int*)take((size_t)(NB_DC + 1) * 256 * sizeof(int));
    int*    dbase    = (int*)take((size_t)(NB_DC + 1) * 256 * sizeof(int));
    int*    nodeperm = (int*)take((size_t)N * sizeof(int));
    int2*   es       = (int2*)take((size_t)E * sizeof(int2));
    __half* eah      = (__half*)take((size_t)E * 16 * sizeof(__half));
    __half* A        = (__half*)take((size_t)N * 64 * sizeof(__half));
    __half* B        = (__half*)take((size_t)N * 64 * sizeof(__half));
    __half* Chalf    = (__half*)take((size_t)N * 64 * sizeof(__half));
    __half* Wf1      = (__half*)take((size_t)128 * 128 * sizeof(__half));
    __half* Wf2      = (__half*)take((size_t)64 * 64 * sizeof(__half));

    // ---- CSR build + weight repack ----
    (void)hipMemsetAsync(deg, 0, (size_t)(zero_end - (char*)deg), stream);
    hist_kernel<<<(E + 255) / 256, 256, 0, stream>>>(dst, deg, E);
    {
        int nb = (N + 1023) / 1024;
        scan_part<<<nb, 256, 0, stream>>>(deg, bsum, N);
        scan_mid<<<1, 128, 0, stream>>>(bsum, rowstart, nb, N);
        scan_fin<<<nb, 256, 0, stream>>>(deg, bsum, rowstart, cursor, N);
    }
    wprep_both<<<80, 256, 0, stream>>>(W1l, W1r, Wf1, W2l, W2r, Wf2);

    // ---- FAT: gemm1 || scatter || dcount ----
    {
        int nbG = (N + 63) / 64;
        int nbS = (E + 255) / 256;
        fat_kernel<<<nbG + nbS + NB_DC, 256, 0, stream>>>(
            nbG, nbS, x, Wf1, b1l, b1r, A, B, N, src, dst, eattr, cursor, es, eah, E,
            deg, counts);
    }
    dbase_kernel<<<1, 256, 0, stream>>>(counts, dbase, NB_DC);
    dscatter_block<<<NB_DC, 256, 0, stream>>>(deg, dbase, nodeperm, N);

    // ---- Layer 1: H=2, C=32 (2 nodes/wave) ----
    {
        long waves = (N + 1) / 2;
        fused_edge_agg<2, 32><<<(int)((waves * 64 + 255) / 256), 256, 0, stream>>>(
            rowstart, es, eah, nodeperm, W1e, att1, A, B, bias1, Chalf, N);
    }

    // ---- Layer 2: H=1, C=32 (4 nodes/wave) ----
    gemm_mfma_h<64, 32, 128><<<(N + 127) / 128, 256, 0, stream>>>(Chalf, Wf2, b2l, b2r, A, B, N);
    {
        long waves = (N + 3) / 4;
        fused_edge_agg<1, 32><<<(int)((waves * 64 + 255) / 256), 256, 0, stream>>>(
            rowstart, es, eah, nodeperm, W2e, att2, A, B, bias2, Chalf, N);
    }

    // ---- Final linear ----
    linear_kernel<32, 32, 8><<<(N + 7) / 8, 256, 0, stream>>>(Chalf, Wlin, blin, (float*)d_out, N);
}